// Round 4
// baseline (154.580 us; speedup 1.0000x reference)
//
#include <hip/hip_runtime.h>

// Chamfer distance K=1 NN, both directions. N=4, P1=P2=8192, D=3, fp32.
//
// Numerics: bitwise-replicate numpy fp32:
//   d2 = (sp + sq) - 2.0f * (((px*qx) + (py*qy)) + (pz*qz))
// fp contract OFF for all C-level FP; packed math done with explicit
// v_pk_*_f32 inline asm (per-element rounding identical to scalar VALU).
// Final mul+sub folded to fma(-2,dot,t1): bitwise-safe (x2.0 is exact).
//
// Structure:
//   prep : SoA [X|Y|Z|S] (65536 each) in ws; S = ((x*x)+(y*y))+(z*z).
//   nn   : 1024 blocks x 512 thr. block = 64 queries x 8 waves; wave w
//          scans targets [w*1024,(w+1)*1024) with wave-uniform scalar
//          loads (v2f pairs in SGPRs -> VOP3P packed operands),
//          16 targets/iter, per-16 min tree + winning-iter tracking,
//          exact index via descending scalar rescan (bitwise-identical),
//          LDS reduce across 8 waves (smallest-index tie-break),
//          write out directly. No merge kernel.

typedef float v2f __attribute__((ext_vector_type(2)));

#define NPTS 32768
#define TSEG 1024
#define UN 16

// ws float offsets
#define OFF_X 0
#define OFF_Y 65536
#define OFF_Z 131072
#define OFF_S 196608

__device__ __forceinline__ v2f pk_mul_sv(v2f s, v2f v) {
    v2f d; asm("v_pk_mul_f32 %0, %1, %2" : "=v"(d) : "s"(s), "v"(v)); return d;
}
__device__ __forceinline__ v2f pk_add_sv(v2f s, v2f v) {
    v2f d; asm("v_pk_add_f32 %0, %1, %2" : "=v"(d) : "s"(s), "v"(v)); return d;
}
__device__ __forceinline__ v2f pk_add_vv(v2f a, v2f b) {
    v2f d; asm("v_pk_add_f32 %0, %1, %2" : "=v"(d) : "v"(a), "v"(b)); return d;
}
__device__ __forceinline__ v2f pk_fma_vvv(v2f a, v2f b, v2f c) {
    v2f d; asm("v_pk_fma_f32 %0, %1, %2, %3" : "=v"(d) : "v"(a), "v"(b), "v"(c)); return d;
}

__global__ __launch_bounds__(256) void chamfer_prep(const float* __restrict__ x,
                                                    const float* __restrict__ y,
                                                    float* __restrict__ ws) {
#pragma clang fp contract(off)
    int i = blockIdx.x * 256 + threadIdx.x;     // 0..65535
    const float* src = (i < NPTS) ? x : y;
    int j = (i < NPTS) ? i : (i - NPTS);
    float a = src[j * 3 + 0];
    float b = src[j * 3 + 1];
    float c = src[j * 3 + 2];
    ws[OFF_X + i] = a;
    ws[OFF_Y + i] = b;
    ws[OFF_Z + i] = c;
    ws[OFF_S + i] = ((a * a) + (b * b)) + (c * c);
}

__global__ __launch_bounds__(512, 8) void chamfer_nn(const float* __restrict__ ws,
                                                     float* __restrict__ out) {
#pragma clang fp contract(off)
    int b   = blockIdx.x;            // 0..1023
    int dir = b >> 9;                // 0: x->y, 1: y->x
    int r   = b & 511;
    int n   = r >> 7;                // batch
    int qg  = r & 127;               // query group of 64
    int lane = threadIdx.x & 63;
    int wv   = threadIdx.x >> 6;     // wave id 0..7 = target segment

    const float* X = ws + OFF_X;
    const float* Y = ws + OFF_Y;
    const float* Z = ws + OFF_Z;
    const float* S = ws + OFF_S;

    int qidx   = (dir ? NPTS : 0) + n * 8192 + qg * 64 + lane;
    int tcbase = (dir ? 0 : NPTS) + n * 8192;   // target cloud base
    int tbase  = tcbase + wv * TSEG;            // this wave's segment

    float px = X[qidx], py = Y[qidx], pz = Z[qidx], sp = S[qidx];
    v2f px2 = {px, px}, py2 = {py, py}, pz2 = {pz, pz}, sp2 = {sp, sp};
    v2f n2  = {-2.0f, -2.0f};

    const v2f* X2 = (const v2f*)X;
    const v2f* Y2 = (const v2f*)Y;
    const v2f* Z2 = (const v2f*)Z;
    const v2f* S2 = (const v2f*)S;

    float best = __builtin_inff();
    int bblk = 0;

    for (int blk = 0; blk < TSEG / UN; ++blk) {
        int t0 = __builtin_amdgcn_readfirstlane(tbase + blk * UN);
        int p0 = t0 >> 1;                       // v2f pair index (even, 64B-aligned)
        float pm[UN / 2];
#pragma unroll
        for (int i = 0; i < UN / 2; ++i) {
            v2f xv = X2[p0 + i];
            v2f yv = Y2[p0 + i];
            v2f zv = Z2[p0 + i];
            v2f sv = S2[p0 + i];
            v2f m1  = pk_mul_sv(xv, px2);       // px*qx
            v2f m2  = pk_mul_sv(yv, py2);       // py*qy
            v2f m3  = pk_mul_sv(zv, pz2);       // pz*qz
            v2f a1  = pk_add_vv(m1, m2);        // (..)+(..)
            v2f dot = pk_add_vv(a1, m3);        // +(..)
            v2f t1  = pk_add_sv(sv, sp2);       // sp+sq (commutative, bitwise-same)
            v2f t   = pk_fma_vvv(n2, dot, t1);  // t1 - 2*dot (exact fold)
            pm[i] = fminf(t.x, t.y);
        }
        float m01 = fminf(pm[0], pm[1]);
        float m23 = fminf(pm[2], pm[3]);
        float m45 = fminf(pm[4], pm[5]);
        float m67 = fminf(pm[6], pm[7]);
        float m = fminf(fminf(m01, m23), fminf(m45, m67));
        if (m < best) { best = m; bblk = blk; }   // strict <: earliest iter wins
    }

    // rescan winning 16-target group; scalar VALU rounds identically to
    // packed, so == against best is exact. Descending j: final = smallest idx.
    int t0 = tbase + bblk * UN;
    int idx = t0;
#pragma unroll
    for (int j = UN - 1; j >= 0; --j) {
        float qx = X[t0 + j], qy = Y[t0 + j], qz = Z[t0 + j], qs = S[t0 + j];
        float dot = ((px * qx) + (py * qy)) + (pz * qz);
        float t1  = sp + qs;
        float t   = fmaf(-2.0f, dot, t1);
        if (t == best) idx = t0 + j;
    }

    // cross-wave reduction (8 waves = 8 ascending target segments)
    __shared__ float sval[512];
    __shared__ int   sidx[512];
    sval[threadIdx.x] = best;
    sidx[threadIdx.x] = idx;
    __syncthreads();

    if (threadIdx.x < 64) {
        float bv = sval[threadIdx.x];
        int   bi = sidx[threadIdx.x];
#pragma unroll
        for (int w = 1; w < 8; ++w) {
            float v  = sval[w * 64 + threadIdx.x];
            int   i2 = sidx[w * 64 + threadIdx.x];
            if (v < bv || (v == bv && i2 < bi)) { bv = v; bi = i2; }
        }
        // out layout: cham_x[32768] cham_y[32768] idx_x[32768] idx_y[32768]
        int distoff = dir ? 32768 : 0;
        int idxoff  = dir ? 98304 : 65536;
        int o = n * 8192 + qg * 64 + threadIdx.x;
        out[distoff + o] = bv;
        out[idxoff + o]  = (float)(bi - tcbase);
    }
}

extern "C" void kernel_launch(void* const* d_in, const int* in_sizes, int n_in,
                              void* d_out, int out_size, void* d_ws, size_t ws_size,
                              hipStream_t stream) {
    const float* x = (const float*)d_in[0];
    const float* y = (const float*)d_in[1];
    float* ws  = (float*)d_ws;
    float* out = (float*)d_out;

    chamfer_prep<<<256, 256, 0, stream>>>(x, y, ws);
    chamfer_nn<<<1024, 512, 0, stream>>>(ws, out);
}